// Round 27
// baseline (202.548 us; speedup 1.0000x reference)
//
#include <hip/hip_runtime.h>

#define DM   1024
#define DI   2048
#define LSEQ 1024
#define BSZ  2
#define MROWS (BSZ*LSEQ)   // 2048
#define NCH   (BSZ*DI)     // 4096
#define SCHUNK 32
#define STEPS  32
#define PLANE  (NCH*16)    // 65536

typedef __attribute__((ext_vector_type(4)))  float  f32x4;
typedef __attribute__((ext_vector_type(8)))  __bf16 bf16x8;
typedef __attribute__((ext_vector_type(8)))  unsigned short u16x8;

__device__ __forceinline__ unsigned short f2bf(float f) {
  union { float f; unsigned int u; } v; v.f = f;
  unsigned int u = v.u;
  unsigned int r = (u + 0x7fffu + ((u >> 16) & 1u)) >> 16;  // RNE
  return (unsigned short)r;
}
__device__ __forceinline__ float bf2f(unsigned short h) {
  union { unsigned int u; float f; } v; v.u = (unsigned int)h << 16; return v.f;
}

__device__ __forceinline__ void load_lds16(const void* g, void* l) {
  __builtin_amdgcn_global_load_lds((const __attribute__((address_space(1))) void*)g,
                                   (__attribute__((address_space(3))) void*)l, 16, 0, 0);
}

// ---- prep: LayerNorm+cast (blocks 0..2047) and all weight casts (blocks 2048+) ----
__global__ __launch_bounds__(256) void prep(
    const float* __restrict__ x, const float* __restrict__ nw, const float* __restrict__ nb,
    unsigned short* __restrict__ xn_bf,
    const float* __restrict__ s0, unsigned short* __restrict__ d0,
    const float* __restrict__ s1, unsigned short* __restrict__ d1,
    const float* __restrict__ s2, unsigned short* __restrict__ d2,
    const float* __restrict__ s3, unsigned short* __restrict__ d3)
{
  int tid = threadIdx.x;
  if (blockIdx.x < MROWS) {
    int row = blockIdx.x;
    const float4* xr = (const float4*)(x + (size_t)row * DM);
    float4 v = xr[tid];
    float s  = v.x + v.y + v.z + v.w;
    float s2v = v.x*v.x + v.y*v.y + v.z*v.z + v.w*v.w;
    #pragma unroll
    for (int off = 32; off > 0; off >>= 1) { s += __shfl_down(s, off); s2v += __shfl_down(s2v, off); }
    __shared__ float ss[4], sq[4];
    if ((tid & 63) == 0) { ss[tid >> 6] = s; sq[tid >> 6] = s2v; }
    __syncthreads();
    float mean = (ss[0]+ss[1]+ss[2]+ss[3]) * (1.0f/DM);
    float var  = (sq[0]+sq[1]+sq[2]+sq[3]) * (1.0f/DM) - mean*mean;
    float rs = rsqrtf(var + 1e-5f);
    float4 wv = ((const float4*)nw)[tid];
    float4 bv = ((const float4*)nb)[tid];
    ushort4 o;
    o.x = f2bf((v.x-mean)*rs*wv.x + bv.x);
    o.y = f2bf((v.y-mean)*rs*wv.y + bv.y);
    o.z = f2bf((v.z-mean)*rs*wv.z + bv.z);
    o.w = f2bf((v.w-mean)*rs*wv.w + bv.w);
    ((ushort4*)(xn_bf + (size_t)row * DM))[tid] = o;
  } else {
    const int N0 = 4096*1024/4, N1 = 2048*2048/4, N2 = 1024*2048/4, N3 = 32*2048/4;
    int i = (blockIdx.x - MROWS) * 256 + tid;
    int stride = (gridDim.x - MROWS) * 256;
    int total = N0 + N1 + N2 + N3;
    for (; i < total; i += stride) {
      const float* s; unsigned short* d; int j = i;
      if (j < N0) { s = s0; d = d0; }
      else if ((j -= N0) < N1) { s = s1; d = d1; }
      else if ((j -= N1) < N2) { s = s2; d = d2; }
      else { j -= N2; s = s3; d = d3; }
      float4 v = ((const float4*)s)[j];
      ushort4 o;
      o.x = f2bf(v.x); o.y = f2bf(v.y); o.z = f2bf(v.z); o.w = f2bf(v.w);
      ((ushort4*)d)[j] = o;
    }
  }
}

// ---- bf16 MFMA GEMM, BM=MV*32, BN=NV*32, BK=64, counted-vmcnt 2-deep pipeline ----
// (MV,NV)=(4,2): 128x64.  (2,2): 64x64.
// EPI: 0 plain, 1 softplus, 2 +resid, 3 split-K raw f32 partial (blockIdx.z = K-half).
template<int EPI, int MV, int NV, typename OT>
__global__ __launch_bounds__(256) void gemm_bt(
    const unsigned short* __restrict__ A, const unsigned short* __restrict__ Bw,
    const float* __restrict__ bias, const float* __restrict__ resid,
    OT* __restrict__ C, int N, int K)
{
  constexpr int BM = MV * 32;
  constexpr int BN = NV * 32;
  constexpr int VM = MV + NV;        // vmem ops per tile per thread
  __shared__ unsigned short As[2][BM*64];
  __shared__ unsigned short Bs[2][BN*64];
  const int tid  = threadIdx.x;
  const int lane = tid & 63;
  const int w    = tid >> 6;

  // split-K: this block handles K-range [k0, k0+KS)
  const int KS = (EPI == 3) ? (K >> 1) : K;
  const int k0 = (EPI == 3) ? blockIdx.z * KS : 0;

  // XCD-aware chunked swizzle over x*y (nwg % 8 == 0)
  const int nbx = gridDim.x;
  const int nwg = gridDim.x * gridDim.y;
  int wg  = blockIdx.y * nbx + blockIdx.x;
  int swz = (wg & 7) * (nwg >> 3) + (wg >> 3);
  const int m0 = (swz / nbx) * BM;
  const int n0 = (swz % nbx) * BN;

  const int wm = w >> 1, wn = w & 1;     // wave tile (MV*16) x (NV*16)
  const int r16 = lane & 15;
  const int kg  = lane >> 4;

  const int srow = tid >> 3;                    // 0..31
  const int kl   = (tid & 7) ^ (srow & 7);      // pre-swizzled global k-slot
  const unsigned short* gaBase = A  + (size_t)(m0 + srow) * K + k0 + kl * 8;
  const unsigned short* gbBase = Bw + (size_t)(n0 + srow) * K + k0 + kl * 8;

  f32x4 acc[MV][NV] = {};

  auto stage = [&](int buf, int kt) {
    const unsigned short* ga = gaBase + kt;
    #pragma unroll
    for (int p = 0; p < MV; ++p)
      load_lds16(ga + (size_t)(32*p)*K, (char*)As[buf] + p*4096 + tid*16);
    const unsigned short* gb = gbBase + kt;
    #pragma unroll
    for (int p = 0; p < NV; ++p)
      load_lds16(gb + (size_t)(32*p)*K, (char*)Bs[buf] + p*4096 + tid*16);
  };

  stage(0, 0);
  stage(1, 64);

  int cur = 0;
  for (int kt = 0; kt < KS; kt += 64) {
    if (kt + 64 < KS) asm volatile("s_waitcnt vmcnt(%0)" :: "i"(VM) : "memory");
    else              asm volatile("s_waitcnt vmcnt(0)" ::: "memory");
    __builtin_amdgcn_s_barrier();

    bf16x8 av[2][MV], bv[2][NV];
    #pragma unroll
    for (int kk = 0; kk < 2; ++kk) {
      const int phys = (kk*4 + kg) ^ (r16 & 7);
      #pragma unroll
      for (int i = 0; i < MV; ++i)
        av[kk][i] = *(const bf16x8*)((const char*)As[cur] + (wm*(MV*16) + i*16 + r16)*128 + phys*16);
      #pragma unroll
      for (int j = 0; j < NV; ++j)
        bv[kk][j] = *(const bf16x8*)((const char*)Bs[cur] + (wn*(NV*16) + j*16 + r16)*128 + phys*16);
    }
    #pragma unroll
    for (int kk = 0; kk < 2; ++kk)
      #pragma unroll
      for (int i = 0; i < MV; ++i)
        #pragma unroll
        for (int j = 0; j < NV; ++j)
          acc[i][j] = __builtin_amdgcn_mfma_f32_16x16x32_bf16(av[kk][i], bv[kk][j], acc[i][j], 0, 0, 0);

    asm volatile("s_waitcnt lgkmcnt(0)" ::: "memory");
    __builtin_amdgcn_s_barrier();
    if (kt + 128 < KS) stage(cur, kt + 128);
    cur ^= 1;
  }

  OT* Cb = C;
  if constexpr (EPI == 3) Cb = C + (size_t)blockIdx.z * MROWS * N;

  #pragma unroll
  for (int i = 0; i < MV; ++i) {
    int rbase = m0 + wm*(MV*16) + i*16 + kg*4;
    #pragma unroll
    for (int j = 0; j < NV; ++j) {
      int col = n0 + wn*(NV*16) + j*16 + r16;
      float bcol = (EPI == 3) ? 0.f : bias[col];
      #pragma unroll
      for (int r = 0; r < 4; ++r) {
        int row = rbase + r;
        float v = acc[i][j][r] + bcol;
        if (EPI == 1) v = (v > 20.f) ? v : log1pf(__expf(v));
        if (EPI == 2) v += resid[(size_t)row * N + col];
        if constexpr (sizeof(OT) == 2) Cb[(size_t)row * N + col] = f2bf(v);
        else                           Cb[(size_t)row * N + col] = v;
      }
    }
  }
}

// ---- split-K reduce: out = x + bias + p0 + p1 (float4 vectorized) ----
__global__ __launch_bounds__(256) void reduce_k(const float* __restrict__ p0,
    const float* __restrict__ p1, const float* __restrict__ x,
    const float* __restrict__ bias, float* __restrict__ out)
{
  int i = blockIdx.x * 256 + threadIdx.x;          // float4 index over 2048x1024
  float4 a  = ((const float4*)p0)[i];
  float4 b  = ((const float4*)p1)[i];
  float4 xr = ((const float4*)x)[i];
  int col4 = (i & (DM/4 - 1)) * 4;
  float4 bs = *(const float4*)(bias + col4);
  float4 o;
  o.x = xr.x + bs.x + a.x + b.x;
  o.y = xr.y + bs.y + a.y + b.y;
  o.z = xr.z + bs.z + a.z + b.z;
  o.w = xr.w + bs.w + a.w + b.w;
  ((float4*)out)[i] = o;
}

// ------ depthwise causal conv1d + SiLU, 8 channels/thread (ushort8 loads) ------
__global__ __launch_bounds__(256) void conv_silu(const unsigned short* __restrict__ xz,
    const float* __restrict__ cw, const float* __restrict__ cb,
    unsigned short* __restrict__ u_bf)
{
  int t8 = blockIdx.x * 256 + threadIdx.x;     // 0 .. MROWS*DI/8-1
  int d8 = (t8 << 3) & (DI-1);                 // base channel (8-aligned)
  int m  = t8 >> 8;                            // row (DI/8 = 256 threads per row)
  int l  = m & (LSEQ-1);
  const unsigned short* base = xz + (size_t)m * (2*DI) + d8;
  u16x8 r0 = *(const u16x8*)base;
  u16x8 r1 = (l >= 1) ? *(const u16x8*)(base - (2*DI))   : u16x8{};
  u16x8 r2 = (l >= 2) ? *(const u16x8*)(base - 2*(2*DI)) : u16x8{};
  u16x8 r3 = (l >= 3) ? *(const u16x8*)(base - 3*(2*DI)) : u16x8{};
  float4 cb0 = *(const float4*)(cb + d8);
  float4 cb1 = *(const float4*)(cb + d8 + 4);
  u16x8 o;
  #pragma unroll
  for (int e = 0; e < 8; ++e) {
    int d = d8 + e;
    float w0 = cw[d*4+0], w1 = cw[d*4+1], w2 = cw[d*4+2], w3 = cw[d*4+3];
    float acc = (e < 4) ? ((const float*)&cb0)[e] : ((const float*)&cb1)[e-4];
    acc += w3 * bf2f(r0[e]);
    if (l >= 1) acc += w2 * bf2f(r1[e]);
    if (l >= 2) acc += w1 * bf2f(r2[e]);
    if (l >= 3) acc += w0 * bf2f(r3[e]);
    float s = acc / (1.f + __expf(-acc));
    o[e] = f2bf(s);
  }
  *(u16x8*)(u_bf + (size_t)m * DI + d8) = o;
}

// ---------------- x_proj via MFMA ----------------
__global__ __launch_bounds__(64) void xproj_mfma(const unsigned short* __restrict__ u_bf,
    const unsigned short* __restrict__ wx, const float* __restrict__ bias,
    float* __restrict__ xdb)
{
  int lane = threadIdx.x;
  int m0 = blockIdx.x * 16;
  int r16 = lane & 15, kg = lane >> 4;
  f32x4 acc0 = {}, acc1 = {};
  const unsigned short* ap  = u_bf + (size_t)(m0 + r16) * DI + kg*8;
  const unsigned short* b0p = wx   + (size_t)r16        * DI + kg*8;
  const unsigned short* b1p = wx   + (size_t)(16 + r16) * DI + kg*8;
  #pragma unroll 4
  for (int kt = 0; kt < DI; kt += 32) {
    bf16x8 a  = *(const bf16x8*)(ap  + kt);
    bf16x8 b0 = *(const bf16x8*)(b0p + kt);
    bf16x8 b1 = *(const bf16x8*)(b1p + kt);
    acc0 = __builtin_amdgcn_mfma_f32_16x16x32_bf16(a, b0, acc0, 0, 0, 0);
    acc1 = __builtin_amdgcn_mfma_f32_16x16x32_bf16(a, b1, acc1, 0, 0, 0);
  }
  #pragma unroll
  for (int r = 0; r < 4; ++r) {
    int row = m0 + kg*4 + r;
    xdb[row*32 + r16]      = acc0[r] + bias[r16];
    xdb[row*32 + 16 + r16] = acc1[r] + bias[16 + r16];
  }
}

// ------- chunked selective scan: 4 states/thread, bf16 inputs -------
__global__ __launch_bounds__(256) void scan_p1(const unsigned short* __restrict__ delta,
    const unsigned short* __restrict__ u, const float* __restrict__ xdb,
    const float* __restrict__ A_log, float* __restrict__ agg_a, float* __restrict__ agg_b)
{
  int tid = threadIdx.x;
  int sh  = tid & 3;
  int ch  = blockIdx.x * 64 + (tid >> 2);
  int c   = blockIdx.y;
  int b = ch >> 11, d = ch & (DI-1);
  float Ads[4];
  {
    f32x4 Ar = *(const f32x4*)(A_log + d*16 + sh*4);
    #pragma unroll
    for (int s = 0; s < 4; ++s) Ads[s] = -__expf(Ar[s]);
  }
  float a[4] = {1.f,1.f,1.f,1.f}, bb[4] = {0.f,0.f,0.f,0.f};
  int row0 = b * LSEQ + c * STEPS;
  const unsigned short* dp = delta + (size_t)row0 * DI + d;
  const unsigned short* up = u     + (size_t)row0 * DI + d;
  #pragma unroll 4
  for (int t = 0; t < STEPS; ++t) {
    float dl = bf2f(dp[t*DI]);
    float uu = bf2f(up[t*DI]);
    f32x4 Bv = *(const f32x4*)(xdb + (size_t)(row0 + t) * 32 + sh*4);
    float dlu = dl * uu;
    #pragma unroll
    for (int s = 0; s < 4; ++s) {
      float dA = __expf(dl * Ads[s]);
      bb[s] = fmaf(dA, bb[s], dlu * Bv[s]);
      a[s] *= dA;
    }
  }
  int idx = c*PLANE + ch*16 + sh*4;
  f32x4 av, bv;
  #pragma unroll
  for (int s = 0; s < 4; ++s) { av[s] = a[s]; bv[s] = bb[s]; }
  *(f32x4*)(agg_a + idx) = av;
  *(f32x4*)(agg_b + idx) = bv;
}

__global__ __launch_bounds__(256) void scan_p2(const float* __restrict__ agg_a,
    const float* __restrict__ agg_b, float* __restrict__ hinit)
{
  int idx = blockIdx.x * 256 + threadIdx.x;
  float h = 0.f;
  #pragma unroll
  for (int c = 0; c < SCHUNK; ++c) {
    hinit[c*PLANE + idx] = h;
    h = fmaf(agg_a[c*PLANE + idx], h, agg_b[c*PLANE + idx]);
  }
}

__global__ __launch_bounds__(256) void scan_p3(const unsigned short* __restrict__ delta,
    const unsigned short* __restrict__ u, const float* __restrict__ xdb,
    const float* __restrict__ A_log, const float* __restrict__ Dp,
    const unsigned short* __restrict__ xz, const float* __restrict__ hinit,
    unsigned short* __restrict__ y_bf)
{
  int tid = threadIdx.x;
  int sh  = tid & 3;
  int ch  = blockIdx.x * 64 + (tid >> 2);
  int c   = blockIdx.y;
  int b = ch >> 11, d = ch & (DI-1);
  float Ads[4];
  {
    f32x4 Ar = *(const f32x4*)(A_log + d*16 + sh*4);
    #pragma unroll
    for (int s = 0; s < 4; ++s) Ads[s] = -__expf(Ar[s]);
  }
  float h[4];
  {
    f32x4 hv = *(const f32x4*)(hinit + c*PLANE + ch*16 + sh*4);
    #pragma unroll
    for (int s = 0; s < 4; ++s) h[s] = hv[s];
  }
  float Dd = Dp[d];
  int row0 = b * LSEQ + c * STEPS;
  const unsigned short* dp = delta + (size_t)row0 * DI + d;
  const unsigned short* up = u     + (size_t)row0 * DI + d;
  const unsigned short* zp = xz    + (size_t)row0 * (2*DI) + DI + d;
  unsigned short* yp = y_bf + (size_t)row0 * DI + d;
  #pragma unroll 2
  for (int t = 0; t < STEPS; ++t) {
    float dl = bf2f(dp[t*DI]);
    float uu = bf2f(up[t*DI]);
    const float* xr = xdb + (size_t)(row0 + t) * 32 + sh*4;
    f32x4 Bv = *(const f32x4*)xr;
    f32x4 Cv = *(const f32x4*)(xr + 16);
    float dlu = dl * uu;
    float y = 0.f;
    #pragma unroll
    for (int s = 0; s < 4; ++s) {
      float dA = __expf(dl * Ads[s]);
      h[s] = fmaf(dA, h[s], dlu * Bv[s]);
      y = fmaf(h[s], Cv[s], y);
    }
    y += __shfl_xor(y, 1);
    y += __shfl_xor(y, 2);
    if (sh == 0) {
      float zz = bf2f(zp[t*(2*DI)]);
      float yv = y + uu * Dd;
      yv *= zz / (1.f + __expf(-zz));
      yp[t*DI] = f2bf(yv);
    }
  }
}

extern "C" void kernel_launch(void* const* d_in, const int* in_sizes, int n_in,
                              void* d_out, int out_size, void* d_ws, size_t ws_size,
                              hipStream_t stream)
{
  (void)in_sizes; (void)n_in; (void)out_size;
  const float* x      = (const float*)d_in[0];
  const float* norm_w = (const float*)d_in[1];
  const float* norm_b = (const float*)d_in[2];
  const float* in_w   = (const float*)d_in[3];
  const float* in_b   = (const float*)d_in[4];
  const float* conv_w = (const float*)d_in[5];
  const float* conv_b = (const float*)d_in[6];
  const float* xp_w   = (const float*)d_in[7];
  const float* xp_b   = (const float*)d_in[8];
  const float* dt_w   = (const float*)d_in[9];
  const float* dt_b   = (const float*)d_in[10];
  const float* A_log  = (const float*)d_in[11];
  const float* D_par  = (const float*)d_in[12];
  const float* out_w  = (const float*)d_in[13];
  const float* out_b  = (const float*)d_in[14];
  float* out = (float*)d_out;

  char* p = (char*)d_ws;
  unsigned short* xn_bf = (unsigned short*)p;  p += 2048ull*1024*2;   // 4 MB
  unsigned short* w_in  = (unsigned short*)p;  p += 4096ull*1024*2;   // 8 MB
  unsigned short* w_dt  = (unsigned short*)p;  p += 2048ull*2048*2;   // 8 MB
  unsigned short* w_out = (unsigned short*)p;  p += 1024ull*2048*2;   // 4 MB
  unsigned short* wx_bf = (unsigned short*)p;  p += 32ull*2048*2;     // 128 KB
  unsigned short* xz    = (unsigned short*)p;  p += 2048ull*4096*2;   // 16 MB (bf16)
  unsigned short* u_bf  = (unsigned short*)p;  p += 2048ull*2048*2;   // 8 MB
  float*          xdb   = (float*)p;           p += 2048ull*32*4;     // 256 KB
  unsigned short* delta = (unsigned short*)p;  p += 2048ull*2048*2;   // 8 MB (bf16)
  unsigned short* y_bf  = (unsigned short*)p;  p += 2048ull*2048*2;   // 8 MB
  float*          hinit = (float*)p;           p += (size_t)PLANE*SCHUNK*4; // 8 MB
  if ((size_t)(p - (char*)d_ws) > ws_size) return;

  // overlays (regions dead by the time they're reused):
  float* agg_a = (float*)w_in;   // dead after gemm<0>
  float* agg_b = (float*)w_dt;   // dead after gemm<1>
  // split-K partials: part0 -> w_in region, part1 -> w_dt region (adjacent, 16 MB total;
  // agg_a/agg_b are dead after scan_p2, and gemm<3> runs after scan_p3)
  float* part0 = (float*)w_in;
  float* part1 = (float*)w_dt;

  prep<<<MROWS + 2048, 256, 0, stream>>>(x, norm_w, norm_b, xn_bf,
                                         in_w, w_in, dt_w, w_dt, out_w, w_out, xp_w, wx_bf);

  gemm_bt<0, 4, 2, unsigned short><<<dim3(4096/64, MROWS/128), 256, 0, stream>>>(xn_bf, w_in, in_b, nullptr, xz, 4096, 1024);
  conv_silu<<<(MROWS*DI)/(256*8), 256, 0, stream>>>(xz, conv_w, conv_b, u_bf);
  xproj_mfma<<<MROWS/16, 64, 0, stream>>>(u_bf, wx_bf, xp_b, xdb);
  gemm_bt<1, 4, 2, unsigned short><<<dim3(2048/64, MROWS/128), 256, 0, stream>>>(u_bf, w_dt, dt_b, nullptr, delta, 2048, 2048);

  scan_p1<<<dim3(NCH/64, SCHUNK), 256, 0, stream>>>(delta, u_bf, xdb, A_log, agg_a, agg_b);
  scan_p2<<<PLANE/256, 256, 0, stream>>>(agg_a, agg_b, hinit);
  scan_p3<<<dim3(NCH/64, SCHUNK), 256, 0, stream>>>(delta, u_bf, xdb, A_log, D_par, xz, hinit, y_bf);

  // split-K=2 out-projection with the (4,2) 128x64 tile: 512 blocks (2/CU), 16 K-steps each
  gemm_bt<3, 4, 2, float><<<dim3(1024/64, MROWS/128, 2), 256, 0, stream>>>(y_bf, w_out, out_b, nullptr, part0, 1024, 2048);
  reduce_k<<<(MROWS*DM)/(4*256), 256, 0, stream>>>(part0, part1, x, out_b, out);
}

// Round 28
// 193.832 us; speedup vs baseline: 1.0450x; 1.0450x over previous
//
#include <hip/hip_runtime.h>

#define DM   1024
#define DI   2048
#define LSEQ 1024
#define BSZ  2
#define MROWS (BSZ*LSEQ)   // 2048
#define NCH   (BSZ*DI)     // 4096
#define SCHUNK 32
#define STEPS  32
#define PLANE  (NCH*16)    // 65536

typedef __attribute__((ext_vector_type(4)))  float  f32x4;
typedef __attribute__((ext_vector_type(8)))  __bf16 bf16x8;
typedef __attribute__((ext_vector_type(8)))  unsigned short u16x8;

__device__ __forceinline__ unsigned short f2bf(float f) {
  union { float f; unsigned int u; } v; v.f = f;
  unsigned int u = v.u;
  unsigned int r = (u + 0x7fffu + ((u >> 16) & 1u)) >> 16;  // RNE
  return (unsigned short)r;
}
__device__ __forceinline__ float bf2f(unsigned short h) {
  union { unsigned int u; float f; } v; v.u = (unsigned int)h << 16; return v.f;
}

__device__ __forceinline__ void load_lds16(const void* g, void* l) {
  __builtin_amdgcn_global_load_lds((const __attribute__((address_space(1))) void*)g,
                                   (__attribute__((address_space(3))) void*)l, 16, 0, 0);
}

// ---- prep: LayerNorm+cast (blocks 0..2047) and all weight casts (blocks 2048+) ----
__global__ __launch_bounds__(256) void prep(
    const float* __restrict__ x, const float* __restrict__ nw, const float* __restrict__ nb,
    unsigned short* __restrict__ xn_bf,
    const float* __restrict__ s0, unsigned short* __restrict__ d0,
    const float* __restrict__ s1, unsigned short* __restrict__ d1,
    const float* __restrict__ s2, unsigned short* __restrict__ d2,
    const float* __restrict__ s3, unsigned short* __restrict__ d3)
{
  int tid = threadIdx.x;
  if (blockIdx.x < MROWS) {
    int row = blockIdx.x;
    const float4* xr = (const float4*)(x + (size_t)row * DM);
    float4 v = xr[tid];
    float s  = v.x + v.y + v.z + v.w;
    float s2v = v.x*v.x + v.y*v.y + v.z*v.z + v.w*v.w;
    #pragma unroll
    for (int off = 32; off > 0; off >>= 1) { s += __shfl_down(s, off); s2v += __shfl_down(s2v, off); }
    __shared__ float ss[4], sq[4];
    if ((tid & 63) == 0) { ss[tid >> 6] = s; sq[tid >> 6] = s2v; }
    __syncthreads();
    float mean = (ss[0]+ss[1]+ss[2]+ss[3]) * (1.0f/DM);
    float var  = (sq[0]+sq[1]+sq[2]+sq[3]) * (1.0f/DM) - mean*mean;
    float rs = rsqrtf(var + 1e-5f);
    float4 wv = ((const float4*)nw)[tid];
    float4 bv = ((const float4*)nb)[tid];
    ushort4 o;
    o.x = f2bf((v.x-mean)*rs*wv.x + bv.x);
    o.y = f2bf((v.y-mean)*rs*wv.y + bv.y);
    o.z = f2bf((v.z-mean)*rs*wv.z + bv.z);
    o.w = f2bf((v.w-mean)*rs*wv.w + bv.w);
    ((ushort4*)(xn_bf + (size_t)row * DM))[tid] = o;
  } else {
    const int N0 = 4096*1024/4, N1 = 2048*2048/4, N2 = 1024*2048/4, N3 = 32*2048/4;
    int i = (blockIdx.x - MROWS) * 256 + tid;
    int stride = (gridDim.x - MROWS) * 256;
    int total = N0 + N1 + N2 + N3;
    for (; i < total; i += stride) {
      const float* s; unsigned short* d; int j = i;
      if (j < N0) { s = s0; d = d0; }
      else if ((j -= N0) < N1) { s = s1; d = d1; }
      else if ((j -= N1) < N2) { s = s2; d = d2; }
      else { j -= N2; s = s3; d = d3; }
      float4 v = ((const float4*)s)[j];
      ushort4 o;
      o.x = f2bf(v.x); o.y = f2bf(v.y); o.z = f2bf(v.z); o.w = f2bf(v.w);
      ((ushort4*)d)[j] = o;
    }
  }
}

// ---- bf16 MFMA GEMM, BM=MV*32, BN=NV*32, BK=64, counted-vmcnt 2-deep pipeline ----
// (MV,NV)=(4,2): 128x64.  (2,2): 64x64.
// EPI: 0 plain, 1 softplus, 2 +resid.
template<int EPI, int MV, int NV, typename OT>
__global__ __launch_bounds__(256) void gemm_bt(
    const unsigned short* __restrict__ A, const unsigned short* __restrict__ Bw,
    const float* __restrict__ bias, const float* __restrict__ resid,
    OT* __restrict__ C, int N, int K)
{
  constexpr int BM = MV * 32;
  constexpr int BN = NV * 32;
  constexpr int VM = MV + NV;        // vmem ops per tile per thread
  __shared__ unsigned short As[2][BM*64];
  __shared__ unsigned short Bs[2][BN*64];
  const int tid  = threadIdx.x;
  const int lane = tid & 63;
  const int w    = tid >> 6;

  // XCD-aware chunked swizzle (nwg % 8 == 0)
  const int nbx = gridDim.x;
  const int nwg = gridDim.x * gridDim.y;
  int wg  = blockIdx.y * nbx + blockIdx.x;
  int swz = (wg & 7) * (nwg >> 3) + (wg >> 3);
  const int m0 = (swz / nbx) * BM;
  const int n0 = (swz % nbx) * BN;

  const int wm = w >> 1, wn = w & 1;     // wave tile (MV*16) x (NV*16)
  const int r16 = lane & 15;
  const int kg  = lane >> 4;

  const int srow = tid >> 3;                    // 0..31
  const int kl   = (tid & 7) ^ (srow & 7);      // pre-swizzled global k-slot
  const unsigned short* gaBase = A  + (size_t)(m0 + srow) * K + kl * 8;
  const unsigned short* gbBase = Bw + (size_t)(n0 + srow) * K + kl * 8;

  f32x4 acc[MV][NV] = {};

  auto stage = [&](int buf, int kt) {
    const unsigned short* ga = gaBase + kt;
    #pragma unroll
    for (int p = 0; p < MV; ++p)
      load_lds16(ga + (size_t)(32*p)*K, (char*)As[buf] + p*4096 + tid*16);
    const unsigned short* gb = gbBase + kt;
    #pragma unroll
    for (int p = 0; p < NV; ++p)
      load_lds16(gb + (size_t)(32*p)*K, (char*)Bs[buf] + p*4096 + tid*16);
  };

  stage(0, 0);
  stage(1, 64);

  int cur = 0;
  for (int kt = 0; kt < K; kt += 64) {
    if (kt + 64 < K) asm volatile("s_waitcnt vmcnt(%0)" :: "i"(VM) : "memory");
    else             asm volatile("s_waitcnt vmcnt(0)" ::: "memory");
    __builtin_amdgcn_s_barrier();

    bf16x8 av[2][MV], bv[2][NV];
    #pragma unroll
    for (int kk = 0; kk < 2; ++kk) {
      const int phys = (kk*4 + kg) ^ (r16 & 7);
      #pragma unroll
      for (int i = 0; i < MV; ++i)
        av[kk][i] = *(const bf16x8*)((const char*)As[cur] + (wm*(MV*16) + i*16 + r16)*128 + phys*16);
      #pragma unroll
      for (int j = 0; j < NV; ++j)
        bv[kk][j] = *(const bf16x8*)((const char*)Bs[cur] + (wn*(NV*16) + j*16 + r16)*128 + phys*16);
    }
    #pragma unroll
    for (int kk = 0; kk < 2; ++kk)
      #pragma unroll
      for (int i = 0; i < MV; ++i)
        #pragma unroll
        for (int j = 0; j < NV; ++j)
          acc[i][j] = __builtin_amdgcn_mfma_f32_16x16x32_bf16(av[kk][i], bv[kk][j], acc[i][j], 0, 0, 0);

    asm volatile("s_waitcnt lgkmcnt(0)" ::: "memory");
    __builtin_amdgcn_s_barrier();
    if (kt + 128 < K) stage(cur, kt + 128);
    cur ^= 1;
  }

  #pragma unroll
  for (int i = 0; i < MV; ++i) {
    int rbase = m0 + wm*(MV*16) + i*16 + kg*4;
    #pragma unroll
    for (int j = 0; j < NV; ++j) {
      int col = n0 + wn*(NV*16) + j*16 + r16;
      float bcol = bias[col];
      #pragma unroll
      for (int r = 0; r < 4; ++r) {
        int row = rbase + r;
        float v = acc[i][j][r] + bcol;
        if (EPI == 1) v = (v > 20.f) ? v : log1pf(__expf(v));
        if (EPI == 2) v += resid[(size_t)row * N + col];
        if constexpr (sizeof(OT) == 2) C[(size_t)row * N + col] = f2bf(v);
        else                           C[(size_t)row * N + col] = v;
      }
    }
  }
}

// ------ depthwise causal conv1d + SiLU, 8 channels/thread (ushort8 loads) ------
__global__ __launch_bounds__(256) void conv_silu(const unsigned short* __restrict__ xz,
    const float* __restrict__ cw, const float* __restrict__ cb,
    unsigned short* __restrict__ u_bf)
{
  int t8 = blockIdx.x * 256 + threadIdx.x;     // 0 .. MROWS*DI/8-1
  int d8 = (t8 << 3) & (DI-1);                 // base channel (8-aligned)
  int m  = t8 >> 8;                            // row (DI/8 = 256 threads per row)
  int l  = m & (LSEQ-1);
  const unsigned short* base = xz + (size_t)m * (2*DI) + d8;
  u16x8 r0 = *(const u16x8*)base;
  u16x8 r1 = (l >= 1) ? *(const u16x8*)(base - (2*DI))   : u16x8{};
  u16x8 r2 = (l >= 2) ? *(const u16x8*)(base - 2*(2*DI)) : u16x8{};
  u16x8 r3 = (l >= 3) ? *(const u16x8*)(base - 3*(2*DI)) : u16x8{};
  float4 cb0 = *(const float4*)(cb + d8);
  float4 cb1 = *(const float4*)(cb + d8 + 4);
  u16x8 o;
  #pragma unroll
  for (int e = 0; e < 8; ++e) {
    int d = d8 + e;
    float w0 = cw[d*4+0], w1 = cw[d*4+1], w2 = cw[d*4+2], w3 = cw[d*4+3];
    float acc = (e < 4) ? ((const float*)&cb0)[e] : ((const float*)&cb1)[e-4];
    acc += w3 * bf2f(r0[e]);
    if (l >= 1) acc += w2 * bf2f(r1[e]);
    if (l >= 2) acc += w1 * bf2f(r2[e]);
    if (l >= 3) acc += w0 * bf2f(r3[e]);
    float s = acc / (1.f + __expf(-acc));
    o[e] = f2bf(s);
  }
  *(u16x8*)(u_bf + (size_t)m * DI + d8) = o;
}

// ---- x_proj via MFMA, 4-wave K-split + LDS reduce ----
__global__ __launch_bounds__(256) void xproj_mfma(const unsigned short* __restrict__ u_bf,
    const unsigned short* __restrict__ wx, const float* __restrict__ bias,
    float* __restrict__ xdb)
{
  __shared__ float red[4][64][9];    // +1 pad: conflict-free
  int tid  = threadIdx.x;
  int lane = tid & 63;
  int kw   = tid >> 6;               // wave id 0..3, owns K slice kw*512..+512
  int m0 = blockIdx.x * 16;
  int r16 = lane & 15, kg = lane >> 4;
  f32x4 acc0 = {}, acc1 = {};
  const unsigned short* ap  = u_bf + (size_t)(m0 + r16) * DI + kw*512 + kg*8;
  const unsigned short* b0p = wx   + (size_t)r16        * DI + kw*512 + kg*8;
  const unsigned short* b1p = wx   + (size_t)(16 + r16) * DI + kw*512 + kg*8;
  #pragma unroll 4
  for (int kt = 0; kt < 512; kt += 32) {
    bf16x8 a  = *(const bf16x8*)(ap  + kt);
    bf16x8 b0 = *(const bf16x8*)(b0p + kt);
    bf16x8 b1 = *(const bf16x8*)(b1p + kt);
    acc0 = __builtin_amdgcn_mfma_f32_16x16x32_bf16(a, b0, acc0, 0, 0, 0);
    acc1 = __builtin_amdgcn_mfma_f32_16x16x32_bf16(a, b1, acc1, 0, 0, 0);
  }
  #pragma unroll
  for (int r = 0; r < 4; ++r) { red[kw][lane][r] = acc0[r]; red[kw][lane][4+r] = acc1[r]; }
  __syncthreads();
  if (kw == 0) {
    #pragma unroll
    for (int r = 0; r < 4; ++r) {
      float s0 = red[0][lane][r]   + red[1][lane][r]   + red[2][lane][r]   + red[3][lane][r];
      float s1 = red[0][lane][4+r] + red[1][lane][4+r] + red[2][lane][4+r] + red[3][lane][4+r];
      int row = m0 + kg*4 + r;
      xdb[row*32 + r16]      = s0 + bias[r16];
      xdb[row*32 + 16 + r16] = s1 + bias[16 + r16];
    }
  }
}

// ------- chunked selective scan: 4 states/thread, bf16 inputs -------
__global__ __launch_bounds__(256) void scan_p1(const unsigned short* __restrict__ delta,
    const unsigned short* __restrict__ u, const float* __restrict__ xdb,
    const float* __restrict__ A_log, float* __restrict__ agg_a, float* __restrict__ agg_b)
{
  int tid = threadIdx.x;
  int sh  = tid & 3;
  int ch  = blockIdx.x * 64 + (tid >> 2);
  int c   = blockIdx.y;
  int b = ch >> 11, d = ch & (DI-1);
  float Ads[4];
  {
    f32x4 Ar = *(const f32x4*)(A_log + d*16 + sh*4);
    #pragma unroll
    for (int s = 0; s < 4; ++s) Ads[s] = -__expf(Ar[s]);
  }
  float a[4] = {1.f,1.f,1.f,1.f}, bb[4] = {0.f,0.f,0.f,0.f};
  int row0 = b * LSEQ + c * STEPS;
  const unsigned short* dp = delta + (size_t)row0 * DI + d;
  const unsigned short* up = u     + (size_t)row0 * DI + d;
  #pragma unroll 4
  for (int t = 0; t < STEPS; ++t) {
    float dl = bf2f(dp[t*DI]);
    float uu = bf2f(up[t*DI]);
    f32x4 Bv = *(const f32x4*)(xdb + (size_t)(row0 + t) * 32 + sh*4);
    float dlu = dl * uu;
    #pragma unroll
    for (int s = 0; s < 4; ++s) {
      float dA = __expf(dl * Ads[s]);
      bb[s] = fmaf(dA, bb[s], dlu * Bv[s]);
      a[s] *= dA;
    }
  }
  int idx = c*PLANE + ch*16 + sh*4;
  f32x4 av, bv;
  #pragma unroll
  for (int s = 0; s < 4; ++s) { av[s] = a[s]; bv[s] = bb[s]; }
  *(f32x4*)(agg_a + idx) = av;
  *(f32x4*)(agg_b + idx) = bv;
}

__global__ __launch_bounds__(256) void scan_p2(const float* __restrict__ agg_a,
    const float* __restrict__ agg_b, float* __restrict__ hinit)
{
  int idx = blockIdx.x * 256 + threadIdx.x;
  float h = 0.f;
  #pragma unroll
  for (int c = 0; c < SCHUNK; ++c) {
    hinit[c*PLANE + idx] = h;
    h = fmaf(agg_a[c*PLANE + idx], h, agg_b[c*PLANE + idx]);
  }
}

__global__ __launch_bounds__(256) void scan_p3(const unsigned short* __restrict__ delta,
    const unsigned short* __restrict__ u, const float* __restrict__ xdb,
    const float* __restrict__ A_log, const float* __restrict__ Dp,
    const unsigned short* __restrict__ xz, const float* __restrict__ hinit,
    unsigned short* __restrict__ y_bf)
{
  int tid = threadIdx.x;
  int sh  = tid & 3;
  int ch  = blockIdx.x * 64 + (tid >> 2);
  int c   = blockIdx.y;
  int b = ch >> 11, d = ch & (DI-1);
  float Ads[4];
  {
    f32x4 Ar = *(const f32x4*)(A_log + d*16 + sh*4);
    #pragma unroll
    for (int s = 0; s < 4; ++s) Ads[s] = -__expf(Ar[s]);
  }
  float h[4];
  {
    f32x4 hv = *(const f32x4*)(hinit + c*PLANE + ch*16 + sh*4);
    #pragma unroll
    for (int s = 0; s < 4; ++s) h[s] = hv[s];
  }
  float Dd = Dp[d];
  int row0 = b * LSEQ + c * STEPS;
  const unsigned short* dp = delta + (size_t)row0 * DI + d;
  const unsigned short* up = u     + (size_t)row0 * DI + d;
  const unsigned short* zp = xz    + (size_t)row0 * (2*DI) + DI + d;
  unsigned short* yp = y_bf + (size_t)row0 * DI + d;
  #pragma unroll 2
  for (int t = 0; t < STEPS; ++t) {
    float dl = bf2f(dp[t*DI]);
    float uu = bf2f(up[t*DI]);
    const float* xr = xdb + (size_t)(row0 + t) * 32 + sh*4;
    f32x4 Bv = *(const f32x4*)xr;
    f32x4 Cv = *(const f32x4*)(xr + 16);
    float dlu = dl * uu;
    float y = 0.f;
    #pragma unroll
    for (int s = 0; s < 4; ++s) {
      float dA = __expf(dl * Ads[s]);
      h[s] = fmaf(dA, h[s], dlu * Bv[s]);
      y = fmaf(h[s], Cv[s], y);
    }
    y += __shfl_xor(y, 1);
    y += __shfl_xor(y, 2);
    if (sh == 0) {
      float zz = bf2f(zp[t*(2*DI)]);
      float yv = y + uu * Dd;
      yv *= zz / (1.f + __expf(-zz));
      yp[t*DI] = f2bf(yv);
    }
  }
}

extern "C" void kernel_launch(void* const* d_in, const int* in_sizes, int n_in,
                              void* d_out, int out_size, void* d_ws, size_t ws_size,
                              hipStream_t stream)
{
  (void)in_sizes; (void)n_in; (void)out_size;
  const float* x      = (const float*)d_in[0];
  const float* norm_w = (const float*)d_in[1];
  const float* norm_b = (const float*)d_in[2];
  const float* in_w   = (const float*)d_in[3];
  const float* in_b   = (const float*)d_in[4];
  const float* conv_w = (const float*)d_in[5];
  const float* conv_b = (const float*)d_in[6];
  const float* xp_w   = (const float*)d_in[7];
  const float* xp_b   = (const float*)d_in[8];
  const float* dt_w   = (const float*)d_in[9];
  const float* dt_b   = (const float*)d_in[10];
  const float* A_log  = (const float*)d_in[11];
  const float* D_par  = (const float*)d_in[12];
  const float* out_w  = (const float*)d_in[13];
  const float* out_b  = (const float*)d_in[14];
  float* out = (float*)d_out;

  char* p = (char*)d_ws;
  unsigned short* xn_bf = (unsigned short*)p;  p += 2048ull*1024*2;   // 4 MB
  unsigned short* w_in  = (unsigned short*)p;  p += 4096ull*1024*2;   // 8 MB
  unsigned short* w_dt  = (unsigned short*)p;  p += 2048ull*2048*2;   // 8 MB
  unsigned short* w_out = (unsigned short*)p;  p += 1024ull*2048*2;   // 4 MB
  unsigned short* wx_bf = (unsigned short*)p;  p += 32ull*2048*2;     // 128 KB
  unsigned short* xz    = (unsigned short*)p;  p += 2048ull*4096*2;   // 16 MB (bf16)
  unsigned short* u_bf  = (unsigned short*)p;  p += 2048ull*2048*2;   // 8 MB
  float*          xdb   = (float*)p;           p += 2048ull*32*4;     // 256 KB
  unsigned short* delta = (unsigned short*)p;  p += 2048ull*2048*2;   // 8 MB (bf16)
  unsigned short* y_bf  = (unsigned short*)p;  p += 2048ull*2048*2;   // 8 MB
  float*          hinit = (float*)p;           p += (size_t)PLANE*SCHUNK*4; // 8 MB
  if ((size_t)(p - (char*)d_ws) > ws_size) return;

  // scan aggregate overlays (dead by scan time):
  float* agg_a = (float*)w_in;   // dead after gemm<0>
  float* agg_b = (float*)w_dt;   // dead after gemm<1>

  prep<<<MROWS + 2048, 256, 0, stream>>>(x, norm_w, norm_b, xn_bf,
                                         in_w, w_in, dt_w, w_dt, out_w, w_out, xp_w, wx_bf);

  gemm_bt<0, 4, 2, unsigned short><<<dim3(4096/64, MROWS/128), 256, 0, stream>>>(xn_bf, w_in, in_b, nullptr, xz, 4096, 1024);
  conv_silu<<<(MROWS*DI)/(256*8), 256, 0, stream>>>(xz, conv_w, conv_b, u_bf);
  xproj_mfma<<<MROWS/16, 256, 0, stream>>>(u_bf, wx_bf, xp_b, xdb);
  gemm_bt<1, 4, 2, unsigned short><<<dim3(2048/64, MROWS/128), 256, 0, stream>>>(u_bf, w_dt, dt_b, nullptr, delta, 2048, 2048);

  scan_p1<<<dim3(NCH/64, SCHUNK), 256, 0, stream>>>(delta, u_bf, xdb, A_log, agg_a, agg_b);
  scan_p2<<<PLANE/256, 256, 0, stream>>>(agg_a, agg_b, hinit);
  scan_p3<<<dim3(NCH/64, SCHUNK), 256, 0, stream>>>(delta, u_bf, xdb, A_log, D_par, xz, hinit, y_bf);

  gemm_bt<2, 2, 2, float><<<dim3(1024/64, MROWS/64), 256, 0, stream>>>(y_bf, w_out, out_b, x, out, 1024, 2048);
}